// Round 3
// baseline (358.787 us; speedup 1.0000x reference)
//
#include <hip/hip_runtime.h>
#include <hip/hip_bf16.h>

#define D_DIM 512
#define NSEQ  4096
#define BATCH 4
#define SCALE 0.125f

typedef __attribute__((ext_vector_type(8)))  short short8;
typedef __attribute__((ext_vector_type(16))) float floatx16;

__device__ __forceinline__ unsigned short f2bf(float f) {
    __hip_bfloat16 h = __float2bfloat16(f);
    return *reinterpret_cast<unsigned short*>(&h);
}

__device__ __forceinline__ floatx16 mfma_bf16(short8 a, short8 b, floatx16 c) {
    return __builtin_amdgcn_mfma_f32_32x32x16_bf16(a, b, c, 0, 0, 0);
}

// ============================================================
// Kernel 1: QKV projection, bf16 MFMA.
// qkv[m][e] = sum_d x[m][d] W[e][d] + b[e]
// Outputs: qs = (q+b)*0.125 [tok][d], kk = k+b [tok][d], vT = (v+b) [b][d][tok]
// ============================================================
#define K1_STRIDE 40   // elems; 80 B rows (16B aligned)

__global__ __launch_bounds__(256, 2) void qkv_gemm(
    const float* __restrict__ x, const float* __restrict__ W,
    const float* __restrict__ bias,
    unsigned short* __restrict__ qs, unsigned short* __restrict__ kk,
    unsigned short* __restrict__ vT)
{
    __shared__ __align__(16) unsigned short Xs[128 * K1_STRIDE];
    __shared__ __align__(16) unsigned short Ws[128 * K1_STRIDE];

    const int t = threadIdx.x;
    const int lane = t & 63, w = t >> 6;
    const int l31 = lane & 31, lh = lane >> 5;
    const int wm = w >> 1, we = w & 1;
    const int m0 = blockIdx.x * 128;
    const int n0 = blockIdx.y * 128;

    floatx16 a00, a01, a10, a11;
#pragma unroll
    for (int r = 0; r < 16; r++) { a00[r] = 0.f; a01[r] = 0.f; a10[r] = 0.f; a11[r] = 0.f; }

    for (int kc = 0; kc < 16; kc++) {
        const int k0 = kc * 32;
        __syncthreads();
#pragma unroll
        for (int p = 0; p < 4; p++) {
            int id = t + p * 256;
            int row = id >> 3, kq = id & 7;
            float4 xv = *(const float4*)(x + (size_t)(m0 + row) * D_DIM + k0 + 4 * kq);
            ushort4 hx; hx.x = f2bf(xv.x); hx.y = f2bf(xv.y); hx.z = f2bf(xv.z); hx.w = f2bf(xv.w);
            *(ushort4*)&Xs[row * K1_STRIDE + 4 * kq] = hx;
            float4 wv = *(const float4*)(W + (size_t)(n0 + row) * D_DIM + k0 + 4 * kq);
            ushort4 hw; hw.x = f2bf(wv.x); hw.y = f2bf(wv.y); hw.z = f2bf(wv.z); hw.w = f2bf(wv.w);
            *(ushort4*)&Ws[row * K1_STRIDE + 4 * kq] = hw;
        }
        __syncthreads();
#pragma unroll
        for (int ks = 0; ks < 2; ks++) {
            const int co = ks * 16 + lh * 8;
            short8 fa0 = *(const short8*)&Xs[(wm * 64 + l31) * K1_STRIDE + co];
            short8 fa1 = *(const short8*)&Xs[(wm * 64 + 32 + l31) * K1_STRIDE + co];
            short8 fb0 = *(const short8*)&Ws[(we * 64 + l31) * K1_STRIDE + co];
            short8 fb1 = *(const short8*)&Ws[(we * 64 + 32 + l31) * K1_STRIDE + co];
            a00 = mfma_bf16(fa0, fb0, a00);
            a01 = mfma_bf16(fa0, fb1, a01);
            a10 = mfma_bf16(fa1, fb0, a10);
            a11 = mfma_bf16(fa1, fb1, a11);
        }
    }

    // epilogue: C/D layout col = lane&31, row = (r&3)+8*(r>>2)+4*lh
#pragma unroll
    for (int jt = 0; jt < 2; jt++) {
        const int e = n0 + we * 64 + jt * 32 + l31;
        const float bv = bias[e];
#pragma unroll
        for (int it = 0; it < 2; it++) {
            const int mb = m0 + wm * 64 + it * 32;
            const floatx16& av = (it == 0) ? ((jt == 0) ? a00 : a01)
                                           : ((jt == 0) ? a10 : a11);
            if (e < 512) {
#pragma unroll
                for (int r = 0; r < 16; r++) {
                    int m = mb + (r & 3) + 8 * (r >> 2) + 4 * lh;
                    qs[(size_t)m * D_DIM + e] = f2bf((av[r] + bv) * SCALE);
                }
            } else if (e < 1024) {
#pragma unroll
                for (int r = 0; r < 16; r++) {
                    int m = mb + (r & 3) + 8 * (r >> 2) + 4 * lh;
                    kk[(size_t)m * D_DIM + (e - 512)] = f2bf(av[r] + bv);
                }
            } else {
                const int d = e - 1024;
#pragma unroll
                for (int q = 0; q < 4; q++) {
                    int mq = mb + 8 * q + 4 * lh;          // 4 consecutive tokens
                    int bb = mq >> 12; int tok = mq & 4095;
                    ushort4 hv;
                    hv.x = f2bf(av[4 * q + 0] + bv); hv.y = f2bf(av[4 * q + 1] + bv);
                    hv.z = f2bf(av[4 * q + 2] + bv); hv.w = f2bf(av[4 * q + 3] + bv);
                    *(ushort4*)&vT[((size_t)bb * 512 + d) * 4096 + tok] = hv;
                }
            }
        }
    }
}

// ============================================================
// Kernel 2: flash attention, bf16 MFMA.
// 512 threads / 8 waves. BQ=64, BK=256. S computed transposed (K·Q^T) so
// softmax row-stats live on lane&31. Waves: wi=w&1 (i-tile), wjj=w>>1
// (j-quarter) for QK^T; wave w owns d-chunk w*64 for PV.
// ============================================================
#define FA_BQ 64
#define FA_BK 256
#define FA_DC 128
#define QC_STR 136
#define KC_STR 136
#define P_STR  264
#define VT_STR 72

__global__ __launch_bounds__(512, 2) void flash_attn(
    const unsigned short* __restrict__ qs, const unsigned short* __restrict__ kk,
    const unsigned short* __restrict__ vT, float* __restrict__ out)
{
    __shared__ __align__(16) unsigned char smem[123392];
    unsigned short* Qc = (unsigned short*)(smem);            // [64][136]  (union w/ Vt)
    unsigned short* Kc = (unsigned short*)(smem + 17408);    // [256][136] (union w/ Vt)
    unsigned short* Vt = (unsigned short*)(smem);            // [512][72]
    unsigned short* P  = (unsigned short*)(smem + 87040);    // [64][264]
    float* pmax    = (float*)(smem + 120832);                // [64][4]
    float* psum    = (float*)(smem + 121856);                // [64][4]
    float* alpha_s = (float*)(smem + 122880);                // [64]
    float* l_s     = (float*)(smem + 123136);                // [64]

    const int t = threadIdx.x;
    const int lane = t & 63, w = t >> 6;
    const int l31 = lane & 31, lh = lane >> 5;
    const int wi = w & 1, wjj = w >> 1;
    const int b  = blockIdx.y;
    const int q0 = blockIdx.x * FA_BQ;
    const size_t qbase = ((size_t)b * NSEQ + q0) * D_DIM;
    const size_t kbase = (size_t)b * NSEQ * D_DIM;
    const size_t vbase = (size_t)b * D_DIM * NSEQ;           // vT[b][d][tok]

    const int i_my = wi * 32 + l31;                          // softmax row (0..63)

    floatx16 o00, o01, o10, o11;                             // o[it][dtt]
#pragma unroll
    for (int r = 0; r < 16; r++) { o00[r] = 0.f; o01[r] = 0.f; o10[r] = 0.f; o11[r] = 0.f; }
    float m_st = -__builtin_inff(), l_st = 0.f;

    for (int kt = 0; kt < NSEQ; kt += FA_BK) {
        // ---------------- S^T = K Q^T ----------------
        floatx16 s0, s1;
#pragma unroll
        for (int r = 0; r < 16; r++) { s0[r] = 0.f; s1[r] = 0.f; }

        for (int dc = 0; dc < D_DIM; dc += FA_DC) {
            __syncthreads();
#pragma unroll
            for (int p = 0; p < 2; p++) {                    // Qc: 64 rows x 128 d
                int id = t + p * 512;
                int row = id >> 4, c8 = id & 15;
                uint4 v = *(const uint4*)(qs + qbase + (size_t)row * D_DIM + dc + c8 * 8);
                *(uint4*)&Qc[row * QC_STR + c8 * 8] = v;
            }
#pragma unroll
            for (int p = 0; p < 8; p++) {                    // Kc: 256 rows x 128 d
                int id = t + p * 512;
                int row = id >> 4, c8 = id & 15;
                uint4 v = *(const uint4*)(kk + kbase + (size_t)(kt + row) * D_DIM + dc + c8 * 8);
                *(uint4*)&Kc[row * KC_STR + c8 * 8] = v;
            }
            __syncthreads();
            const unsigned short* kr0 = &Kc[(wjj * 64 + l31) * KC_STR];
            const unsigned short* kr1 = kr0 + 32 * KC_STR;
            const unsigned short* qr  = &Qc[i_my * QC_STR];
#pragma unroll
            for (int ks = 0; ks < 8; ks++) {
                const int co = ks * 16 + lh * 8;
                short8 fa0 = *(const short8*)(kr0 + co);
                short8 fa1 = *(const short8*)(kr1 + co);
                short8 fb  = *(const short8*)(qr + co);
                s0 = mfma_bf16(fa0, fb, s0);
                s1 = mfma_bf16(fa1, fb, s1);
            }
        }

        // ---------------- online softmax (S^T: col=i on lane&31, rows=j) ----
        float mx = -__builtin_inff();
#pragma unroll
        for (int r = 0; r < 16; r++) mx = fmaxf(mx, fmaxf(s0[r], s1[r]));
        mx = fmaxf(mx, __shfl_xor(mx, 32));
        if (lh == 0) pmax[i_my * 4 + wjj] = mx;
        __syncthreads();
        float4 pm = *(float4*)&pmax[i_my * 4];
        const float m_new = fmaxf(m_st, fmaxf(fmaxf(pm.x, pm.y), fmaxf(pm.z, pm.w)));
        const float alpha = __expf(m_st - m_new);
        m_st = m_new;

        float sum = 0.f;
        {
            const int prow = i_my * P_STR;
#pragma unroll
            for (int q = 0; q < 4; q++) {
                float p0 = __expf(s0[4*q+0] - m_new), p1 = __expf(s0[4*q+1] - m_new);
                float p2 = __expf(s0[4*q+2] - m_new), p3 = __expf(s0[4*q+3] - m_new);
                sum += (p0 + p1) + (p2 + p3);
                ushort4 h; h.x = f2bf(p0); h.y = f2bf(p1); h.z = f2bf(p2); h.w = f2bf(p3);
                *(ushort4*)&P[prow + (wjj*2+0)*32 + 8*q + 4*lh] = h;
            }
#pragma unroll
            for (int q = 0; q < 4; q++) {
                float p0 = __expf(s1[4*q+0] - m_new), p1 = __expf(s1[4*q+1] - m_new);
                float p2 = __expf(s1[4*q+2] - m_new), p3 = __expf(s1[4*q+3] - m_new);
                sum += (p0 + p1) + (p2 + p3);
                ushort4 h; h.x = f2bf(p0); h.y = f2bf(p1); h.z = f2bf(p2); h.w = f2bf(p3);
                *(ushort4*)&P[prow + (wjj*2+1)*32 + 8*q + 4*lh] = h;
            }
        }
        sum += __shfl_xor(sum, 32);
        if (lh == 0) psum[i_my * 4 + wjj] = sum;
        if (lh == 0 && wjj == 0) alpha_s[i_my] = alpha;
        __syncthreads();
        float4 ps = *(float4*)&psum[i_my * 4];
        l_st = l_st * alpha + ((ps.x + ps.y) + (ps.z + ps.w));

        // ---------------- rescale O by alpha (skip if all == 1) -------------
        float av[2][16];
        bool ch = false;
#pragma unroll
        for (int it = 0; it < 2; it++)
#pragma unroll
            for (int q = 0; q < 4; q++) {
                float4 a4 = *(float4*)&alpha_s[it * 32 + 8 * q + 4 * lh];
                av[it][4*q+0] = a4.x; av[it][4*q+1] = a4.y;
                av[it][4*q+2] = a4.z; av[it][4*q+3] = a4.w;
                ch = ch || (a4.x != 1.f) || (a4.y != 1.f) || (a4.z != 1.f) || (a4.w != 1.f);
            }
        if (__any(ch)) {
#pragma unroll
            for (int r = 0; r < 16; r++) {
                o00[r] *= av[0][r]; o01[r] *= av[0][r];
                o10[r] *= av[1][r]; o11[r] *= av[1][r];
            }
        }

        // ---------------- O += P V  (wave w owns d-chunk w*64) --------------
        for (int jc = 0; jc < 4; jc++) {
            __syncthreads();
#pragma unroll
            for (int p = 0; p < 8; p++) {                    // Vt: 512 d x 64 j
                int id = t + p * 512;
                int d = id >> 3, c8 = id & 7;
                uint4 v = *(const uint4*)(vT + vbase + (size_t)d * NSEQ + kt + jc * 64 + c8 * 8);
                *(uint4*)&Vt[d * VT_STR + c8 * 8] = v;
            }
            __syncthreads();
            const unsigned short* pr0 = &P[l31 * P_STR + jc * 64];
            const unsigned short* pr1 = &P[(32 + l31) * P_STR + jc * 64];
            const unsigned short* vr0 = &Vt[(w * 64 + l31) * VT_STR];
            const unsigned short* vr1 = vr0 + 32 * VT_STR;
#pragma unroll
            for (int js = 0; js < 4; js++) {
                const int co = js * 16 + lh * 8;
                short8 pa0 = *(const short8*)(pr0 + co);
                short8 pa1 = *(const short8*)(pr1 + co);
                short8 vb0 = *(const short8*)(vr0 + co);
                short8 vb1 = *(const short8*)(vr1 + co);
                o00 = mfma_bf16(pa0, vb0, o00);
                o01 = mfma_bf16(pa0, vb1, o01);
                o10 = mfma_bf16(pa1, vb0, o10);
                o11 = mfma_bf16(pa1, vb1, o11);
            }
        }
    }

    // ---------------- epilogue: O / l ----------------
    if (lh == 0 && wjj == 0) l_s[i_my] = l_st;
    __syncthreads();
    float iv[2][16];
#pragma unroll
    for (int it = 0; it < 2; it++)
#pragma unroll
        for (int q = 0; q < 4; q++) {
            float4 l4 = *(float4*)&l_s[it * 32 + 8 * q + 4 * lh];
            iv[it][4*q+0] = 1.f / l4.x; iv[it][4*q+1] = 1.f / l4.y;
            iv[it][4*q+2] = 1.f / l4.z; iv[it][4*q+3] = 1.f / l4.w;
        }
#pragma unroll
    for (int it = 0; it < 2; it++) {
        const floatx16& oa = (it == 0) ? o00 : o10;
        const floatx16& ob = (it == 0) ? o01 : o11;
#pragma unroll
        for (int r = 0; r < 16; r++) {
            const int i = it * 32 + (r & 3) + 8 * (r >> 2) + 4 * lh;
            const size_t rowb = ((size_t)b * NSEQ + q0 + i) * D_DIM;
            out[rowb + w * 64 + l31]      = oa[r] * iv[it][r];
            out[rowb + w * 64 + 32 + l31] = ob[r] * iv[it][r];
        }
    }
}

extern "C" void kernel_launch(void* const* d_in, const int* in_sizes, int n_in,
                              void* d_out, int out_size, void* d_ws, size_t ws_size,
                              hipStream_t stream)
{
    (void)in_sizes; (void)n_in; (void)out_size; (void)ws_size;
    const float* x    = (const float*)d_in[0];
    const float* W    = (const float*)d_in[1];
    const float* bias = (const float*)d_in[2];
    float* out = (float*)d_out;

    unsigned short* qs = (unsigned short*)d_ws;              // [16384][512]
    unsigned short* kk = qs + (size_t)16384 * 512;           // [16384][512]
    unsigned short* vT = kk + (size_t)16384 * 512;           // [4][512][4096]

    qkv_gemm<<<dim3(128, 12), 256, 0, stream>>>(x, W, bias, qs, kk, vT);
    flash_attn<<<dim3(NSEQ / FA_BQ, BATCH), 512, 0, stream>>>(qs, kk, vT, out);
}